// Round 7
// baseline (242.343 us; speedup 1.0000x reference)
//
#include <hip/hip_runtime.h>
#include <stdint.h>

typedef __bf16 bf16x8 __attribute__((ext_vector_type(8)));
typedef float  f32x4  __attribute__((ext_vector_type(4)));
typedef uint16_t u16;

#define MAT_ELEMS (1024 * 1024)
#define LDK 1024

// ---------- helpers ----------

__device__ __forceinline__ u16 to_bf16(float f) {
  union { float f; uint32_t u; } v; v.f = f;
  uint32_t u = v.u;
  uint32_t r = u + 0x7FFFu + ((u >> 16) & 1u);   // RNE
  return (u16)(r >> 16);
}

__device__ __forceinline__ float bf16_to_f32(u16 b) {
  union { uint32_t u; float f; } v; v.u = ((uint32_t)b) << 16;
  return v.f;
}

__device__ __forceinline__ void gll16(const void* g, void* l) {
  __builtin_amdgcn_global_load_lds(
      (__attribute__((address_space(1))) void*)const_cast<void*>(g),
      (__attribute__((address_space(3))) void*)(l),
      16, 0, 0);
}

// drain own async loads, align all waves; asm "memory" + sched_barrier keep
// the compiler from moving LDS/global ops across it (rule #18 discipline)
__device__ __forceinline__ void wait_barrier() {
  asm volatile("s_waitcnt vmcnt(0)" ::: "memory");
  __builtin_amdgcn_s_barrier();
  __builtin_amdgcn_sched_barrier(0);
}

__device__ __forceinline__ float fast_sigmoid(float x) {
  x = fminf(fmaxf(x, -30.f), 30.f);
  return 1.0f / (1.0f + __expf(-x));
}

__device__ __forceinline__ float fast_tanh(float x) {
  x = fminf(fmaxf(x, -15.f), 15.f);
  float e = __expf(2.0f * x);
  return (e - 1.0f) / (e + 1.0f);
}

// ---------- prep kernels ----------

struct P8  { const float* p[8]; };
struct P10 { const float* p[10]; };
struct B8  { const float* b[8]; };

__global__ __launch_bounds__(256) void cast8_kernel(P8 s, u16* __restrict__ dst) {
  const float* src = s.p[blockIdx.y];
  u16* d = dst + ((size_t)blockIdx.y << 20);
  int i = (blockIdx.x * 256 + threadIdx.x) * 4;
  f32x4 v = *reinterpret_cast<const f32x4*>(src + i);
  ushort4 o;
  o.x = to_bf16(v[0]); o.y = to_bf16(v[1]);
  o.z = to_bf16(v[2]); o.w = to_bf16(v[3]);
  *reinterpret_cast<ushort4*>(d + i) = o;
}

// transpose+cast 64(src cols) x 32(src rows) tiles; 256B coalesced f32 reads
__global__ __launch_bounds__(256) void transpose_cast_kernel(P10 s, u16* __restrict__ dstbase) {
  __shared__ float tile[32][65];
  const float* src = s.p[blockIdx.z];
  u16* dst = dstbase + ((size_t)blockIdx.z << 20);
  int c0 = blockIdx.x * 64;
  int r0 = blockIdx.y * 32;
  int cl = threadIdx.x & 63;
  int rg = threadIdx.x >> 6;
#pragma unroll
  for (int i = 0; i < 8; ++i) {
    int r = rg + i * 4;
    tile[r][cl] = src[(size_t)(r0 + r) * 1024 + c0 + cl];
  }
  __syncthreads();
  int kl = threadIdx.x & 31;
  int ng = threadIdx.x >> 5;
#pragma unroll
  for (int i = 0; i < 8; ++i) {
    int n = ng + i * 8;
    dst[(size_t)(c0 + n) * 1024 + r0 + kl] = to_bf16(tile[kl][n]);
  }
}

// ---------- GEMM: BM=128 x BN=256, BK=32, 8 waves (2M x 4N, 64x64 each) ----
// A row-major [1024][1024] bf16 (K contiguous); B transposed BT[n][k] bf16.
// LDS: As 128x32, Bs 256x32, double-buffered (48 KB). Bank swizzle: 16B slot
// within each 64B row XORed with (row>>1)&3 (involution), realized by
// pre-swizzling the GLOBAL source column (LDS dest stays linear for gll16)
// and applying the same XOR on the ds_read address.

struct GemmCtx {
  const u16* A; const u16* B;
  int row0, col0;
  int tid, wr, wc, r16, kg, sw;
};

__device__ __forceinline__ void stage_tile(const GemmCtx& c, u16* As, u16* Bs, int kt) {
  int rho = c.tid >> 2;                         // 0..127
  int sig = c.tid & 3;
  int swc = (sig ^ ((c.tid >> 3) & 3)) * 8;     // swizzled 16B-slot, in u16
  int kcol = kt * 32 + swc;
  gll16(c.A + (size_t)(c.row0 + rho) * LDK + kcol, As + c.tid * 8);
  gll16(c.B + (size_t)(c.col0 + rho) * LDK + kcol, Bs + c.tid * 8);
  gll16(c.B + (size_t)(c.col0 + rho + 128) * LDK + kcol, Bs + c.tid * 8 + 4096);
}

__device__ __forceinline__ void compute_tile(const GemmCtx& c, const u16* As,
                                             const u16* Bs, f32x4 acc[4][4]) {
  bf16x8 af[4], bfr[4];
#pragma unroll
  for (int n = 0; n < 4; ++n) {
    int Rb = c.wc * 64 + n * 16 + c.r16;
    bfr[n] = *reinterpret_cast<const bf16x8*>(Bs + Rb * 32 + ((c.kg ^ c.sw) * 8));
  }
#pragma unroll
  for (int m = 0; m < 4; ++m) {
    int Ra = c.wr * 64 + m * 16 + c.r16;
    af[m] = *reinterpret_cast<const bf16x8*>(As + Ra * 32 + ((c.kg ^ c.sw) * 8));
  }
#pragma unroll
  for (int m = 0; m < 4; ++m)
#pragma unroll
    for (int n = 0; n < 4; ++n)
      acc[m][n] = __builtin_amdgcn_mfma_f32_16x16x32_bf16(af[m], bfr[n], acc[m][n], 0, 0, 0);
}

__device__ __forceinline__ void gemm_body(
    const u16* __restrict__ A, const u16* __restrict__ B,
    int row0, int col0, u16* __restrict__ out,
    u16* As0, u16* Bs0, u16* As1, u16* Bs1)
{
  GemmCtx c;
  c.A = A; c.B = B; c.row0 = row0; c.col0 = col0;
  c.tid = threadIdx.x;
  int lane = c.tid & 63;
  int w = c.tid >> 6;                 // 0..7
  c.wr  = w >> 2;                     // 0..1 (64-row half)
  c.wc  = w & 3;                      // 0..3 (64-col quarter)
  c.r16 = lane & 15;
  c.kg  = lane >> 4;                  // 0..3
  c.sw  = (c.r16 >> 1) & 3;           // read-side swizzle (row-dependent term)

  f32x4 acc[4][4];
#pragma unroll
  for (int m = 0; m < 4; ++m)
#pragma unroll
    for (int n = 0; n < 4; ++n) {
      f32x4 z = {0.f, 0.f, 0.f, 0.f};
      acc[m][n] = z;
    }

  stage_tile(c, As0, Bs0, 0);
  wait_barrier();

  for (int kt = 0; kt < 32; kt += 2) {
    stage_tile(c, As1, Bs1, kt + 1);   // issue next-tile loads FIRST (max lead)
    compute_tile(c, As0, Bs0, acc);    // 16 MFMA hide the load latency
    wait_barrier();                    // drain own 3 loads (mostly landed) + align
    if (kt + 2 < 32) stage_tile(c, As0, Bs0, kt + 2);
    compute_tile(c, As1, Bs1, acc);
    wait_barrier();
  }

  // epilogue: D layout col = lane&15, row = (lane>>4)*4 + r  [m89-verified]
#pragma unroll
  for (int m = 0; m < 4; ++m) {
#pragma unroll
    for (int r = 0; r < 4; ++r) {
      int row = row0 + c.wr * 64 + m * 16 + c.kg * 4 + r;
#pragma unroll
      for (int n = 0; n < 4; ++n) {
        int col = col0 + c.wc * 64 + n * 16 + c.r16;
        out[(size_t)row * 1024 + col] = to_bf16(acc[m][n][r]);
      }
    }
  }
}

// chunked XCD swizzle: 256 blocks, 32/XCD = exactly one gate per XCD (4MB L2 fit)
__device__ __forceinline__ void swz_decode(int bx, int& g, int& row0, int& col0) {
  int wg = ((bx & 7) << 5) | (bx >> 3);
  g = wg >> 5;                         // 0..7
  int t = wg & 31;                     // 32 tiles: 8 m x 4 n
  row0 = (t >> 2) * 128;
  col0 = (t & 3) * 256;
}

// stage 1: T_g = L_g @ {x|h}   grid 256 x 512thr
__global__ __launch_bounds__(512) void gemm_stage1_kernel(
    const u16* __restrict__ Lb, const u16* __restrict__ xT,
    const u16* __restrict__ hT, u16* __restrict__ Tbuf)
{
  __shared__ u16 As0[128 * 32], Bs0[256 * 32];
  __shared__ u16 As1[128 * 32], Bs1[256 * 32];
  int g, row0, col0;
  swz_decode(blockIdx.x, g, row0, col0);
  const u16* A = Lb + ((size_t)g << 20);
  const u16* B = (g & 1) ? hT : xT;
  gemm_body(A, B, row0, col0, Tbuf + ((size_t)g << 20), As0, Bs0, As1, Bs1);
}

// stage 2: P_g = T_g @ R_g   grid 256 x 512thr; bias added in cell
__global__ __launch_bounds__(512) void gemm_stage2_kernel(
    const u16* __restrict__ Tbuf, const u16* __restrict__ RT,
    u16* __restrict__ P)
{
  __shared__ u16 As0[128 * 32], Bs0[256 * 32];
  __shared__ u16 As1[128 * 32], Bs1[256 * 32];
  int g, row0, col0;
  swz_decode(blockIdx.x, g, row0, col0);
  const u16* A = Tbuf + ((size_t)g << 20);
  const u16* B = RT   + ((size_t)g << 20);
  gemm_body(A, B, row0, col0, P + ((size_t)g << 20), As0, Bs0, As1, Bs1);
}

// cell: sums gate pairs + biases, applies nonlinearities
__global__ __launch_bounds__(256) void lstm_cell_kernel(
    const u16* __restrict__ P, B8 bp, const float* __restrict__ c,
    float* __restrict__ out)
{
  int i = (blockIdx.x * 256 + threadIdx.x) * 4;
  ushort4 pv[8];
#pragma unroll
  for (int g = 0; g < 8; ++g)
    pv[g] = *reinterpret_cast<const ushort4*>(P + (size_t)g * MAT_ELEMS + i);
  f32x4 bv[8];
#pragma unroll
  for (int g = 0; g < 8; ++g)
    bv[g] = *reinterpret_cast<const f32x4*>(bp.b[g] + i);
  f32x4 cc = *reinterpret_cast<const f32x4*>(c + i);
  f32x4 hn, cn;
#pragma unroll
  for (int j = 0; j < 4; ++j) {
    float pi = bf16_to_f32((&pv[0].x)[j]) + bf16_to_f32((&pv[1].x)[j]) + bv[0][j] + bv[1][j];
    float pf = bf16_to_f32((&pv[2].x)[j]) + bf16_to_f32((&pv[3].x)[j]) + bv[2][j] + bv[3][j];
    float pg = bf16_to_f32((&pv[4].x)[j]) + bf16_to_f32((&pv[5].x)[j]) + bv[4][j] + bv[5][j];
    float po = bf16_to_f32((&pv[6].x)[j]) + bf16_to_f32((&pv[7].x)[j]) + bv[6][j] + bv[7][j];
    float ig = fast_sigmoid(pi);
    float fg = fast_sigmoid(pf);
    float gg = fast_tanh(pg);
    float og = fast_sigmoid(po);
    float cv = fg * cc[j] + ig * gg;
    cn[j] = cv;
    hn[j] = og * fast_tanh(cv);
  }
  *reinterpret_cast<f32x4*>(out + i) = hn;
  *reinterpret_cast<f32x4*>(out + MAT_ELEMS + i) = cn;
}

// ---------- launch ----------

extern "C" void kernel_launch(void* const* d_in, const int* in_sizes, int n_in,
                              void* d_out, int out_size, void* d_ws, size_t ws_size,
                              hipStream_t stream) {
  const float* x = (const float*)d_in[0];
  const float* h = (const float*)d_in[1];
  const float* c = (const float*)d_in[2];

  // ws layout (68 MB):
  u16* Lb   = (u16*)d_ws;                         // 8 x 1M bf16 (16 MB)
  u16* xT   = Lb + ((size_t)8 << 20);             // 2 MB
  u16* hT   = xT + ((size_t)1 << 20);             // 2 MB
  u16* RT   = hT + ((size_t)1 << 20);             // 16 MB
  u16* Tbuf = RT + ((size_t)8 << 20);             // 16 MB
  u16* P    = Tbuf + ((size_t)8 << 20);           // 8 x 1M bf16 (16 MB)

  P8 lp;
  for (int g = 0; g < 8; ++g) lp.p[g] = (const float*)d_in[3 + 3 * g];
  P10 tp;
  tp.p[0] = x; tp.p[1] = h;
  for (int g = 0; g < 8; ++g) tp.p[2 + g] = (const float*)d_in[4 + 3 * g];
  B8 bp;
  for (int g = 0; g < 8; ++g) bp.b[g] = (const float*)d_in[5 + 3 * g];

  cast8_kernel<<<dim3(1024, 8), 256, 0, stream>>>(lp, Lb);
  transpose_cast_kernel<<<dim3(16, 32, 10), 256, 0, stream>>>(tp, xT);
  gemm_stage1_kernel<<<256, 512, 0, stream>>>(Lb, xT, hT, Tbuf);
  gemm_stage2_kernel<<<256, 512, 0, stream>>>(Tbuf, RT, P);
  lstm_cell_kernel<<<1024, 256, 0, stream>>>(P, bp, c, (float*)d_out);
}

// Round 8
// 232.911 us; speedup vs baseline: 1.0405x; 1.0405x over previous
//
#include <hip/hip_runtime.h>
#include <stdint.h>

typedef __bf16 bf16x8 __attribute__((ext_vector_type(8)));
typedef float  f32x4  __attribute__((ext_vector_type(4)));
typedef uint16_t u16;

#define MAT_ELEMS (1024 * 1024)
#define LDK 1024

// ---------- helpers ----------

__device__ __forceinline__ u16 to_bf16(float f) {
  union { float f; uint32_t u; } v; v.f = f;
  uint32_t u = v.u;
  uint32_t r = u + 0x7FFFu + ((u >> 16) & 1u);   // RNE
  return (u16)(r >> 16);
}

__device__ __forceinline__ float bf16_to_f32(u16 b) {
  union { uint32_t u; float f; } v; v.u = ((uint32_t)b) << 16;
  return v.f;
}

__device__ __forceinline__ void gll16(const void* g, void* l) {
  __builtin_amdgcn_global_load_lds(
      (__attribute__((address_space(1))) void*)const_cast<void*>(g),
      (__attribute__((address_space(3))) void*)(l),
      16, 0, 0);
}

// drain own async loads + align waves (rule #18 discipline)
__device__ __forceinline__ void wait_barrier() {
  asm volatile("s_waitcnt vmcnt(0)" ::: "memory");
  __builtin_amdgcn_s_barrier();
  __builtin_amdgcn_sched_barrier(0);
}

__device__ __forceinline__ float fast_sigmoid(float x) {
  x = fminf(fmaxf(x, -30.f), 30.f);
  return 1.0f / (1.0f + __expf(-x));
}

__device__ __forceinline__ float fast_tanh(float x) {
  x = fminf(fmaxf(x, -15.f), 15.f);
  float e = __expf(2.0f * x);
  return (e - 1.0f) / (e + 1.0f);
}

// ---------- prep kernels ----------

struct P8  { const float* p[8]; };
struct P10 { const float* p[10]; };
struct B8  { const float* b[8]; };

__global__ __launch_bounds__(256) void cast8_kernel(P8 s, u16* __restrict__ dst) {
  const float* src = s.p[blockIdx.y];
  u16* d = dst + ((size_t)blockIdx.y << 20);
  int i = (blockIdx.x * 256 + threadIdx.x) * 4;
  f32x4 v = *reinterpret_cast<const f32x4*>(src + i);
  ushort4 o;
  o.x = to_bf16(v[0]); o.y = to_bf16(v[1]);
  o.z = to_bf16(v[2]); o.w = to_bf16(v[3]);
  *reinterpret_cast<ushort4*>(d + i) = o;
}

// transpose+cast 64(src cols) x 32(src rows) tiles; 256B coalesced f32 reads
__global__ __launch_bounds__(256) void transpose_cast_kernel(P10 s, u16* __restrict__ dstbase) {
  __shared__ float tile[32][65];
  const float* src = s.p[blockIdx.z];
  u16* dst = dstbase + ((size_t)blockIdx.z << 20);
  int c0 = blockIdx.x * 64;
  int r0 = blockIdx.y * 32;
  int cl = threadIdx.x & 63;
  int rg = threadIdx.x >> 6;
#pragma unroll
  for (int i = 0; i < 8; ++i) {
    int r = rg + i * 4;
    tile[r][cl] = src[(size_t)(r0 + r) * 1024 + c0 + cl];
  }
  __syncthreads();
  int kl = threadIdx.x & 31;
  int ng = threadIdx.x >> 5;
#pragma unroll
  for (int i = 0; i < 8; ++i) {
    int n = ng + i * 8;
    dst[(size_t)(c0 + n) * 1024 + r0 + kl] = to_bf16(tile[kl][n]);
  }
}

// ---------- GEMM: 128x128 tile, BK=64, 4 waves, dbuf LDS + slot swizzle ----
// A row-major [1024][1024] bf16 (K contiguous); B transposed BT[n][k] bf16.
// LDS tile [128 rows][64 cols bf16] = 128B/row = 8 x 16B slots.
// Swizzle: LDS[row][slot] holds global slot (slot ^ (row&7)) — realized by
// pre-swizzling the GLOBAL source column (LDS dest stays linear for gll16),
// inverted on the read side (involution). Read conflicts: 2-way (free).

struct GemmCtx {
  const u16* A; const u16* B;
  int row0, col0;
  int tid, wr, wc, r16, kg;
};

// stage one 128-row x 64-col operand tile (16KB): 4 issues x 256thr x 16B
__device__ __forceinline__ void stage_op(const u16* __restrict__ src, int base_row,
                                         u16* lds, int kt, int tid) {
  int r = tid >> 3;                              // 0..31 row within issue-group
  int slot = (tid & 7) ^ (r & 7);                // pre-swizzled global slot
  int kcol = kt * 64 + slot * 8;
#pragma unroll
  for (int i = 0; i < 4; ++i)
    gll16(src + (size_t)(base_row + i * 32 + r) * LDK + kcol,
          lds + i * 2048 + tid * 8);
}

__device__ __forceinline__ void stage_tile(const GemmCtx& c, u16* As, u16* Bs, int kt) {
  stage_op(c.A, c.row0, As, kt, c.tid);
  stage_op(c.B, c.col0, Bs, kt, c.tid);
}

__device__ __forceinline__ void compute_tile(const GemmCtx& c, const u16* As,
                                             const u16* Bs, f32x4 acc[4][4]) {
#pragma unroll
  for (int ks = 0; ks < 2; ++ks) {               // two K=32 sub-steps
    bf16x8 af[4], bfr[4];
#pragma unroll
    for (int m = 0; m < 4; ++m) {
      int Ra = c.wr * 64 + m * 16 + c.r16;
      int slot = (ks * 4 + c.kg) ^ (Ra & 7);
      af[m] = *reinterpret_cast<const bf16x8*>(As + Ra * 64 + slot * 8);
    }
#pragma unroll
    for (int n = 0; n < 4; ++n) {
      int Rb = c.wc * 64 + n * 16 + c.r16;
      int slot = (ks * 4 + c.kg) ^ (Rb & 7);
      bfr[n] = *reinterpret_cast<const bf16x8*>(Bs + Rb * 64 + slot * 8);
    }
#pragma unroll
    for (int m = 0; m < 4; ++m)
#pragma unroll
      for (int n = 0; n < 4; ++n)
        acc[m][n] = __builtin_amdgcn_mfma_f32_16x16x32_bf16(af[m], bfr[n], acc[m][n], 0, 0, 0);
  }
}

__device__ __forceinline__ void gemm_body(
    const u16* __restrict__ A, const u16* __restrict__ B,
    int row0, int col0, u16* __restrict__ out,
    u16* As0, u16* Bs0, u16* As1, u16* Bs1)
{
  GemmCtx c;
  c.A = A; c.B = B; c.row0 = row0; c.col0 = col0;
  c.tid = threadIdx.x;
  int lane = c.tid & 63;
  int w = c.tid >> 6;                 // 0..3
  c.wr  = w >> 1;                     // 0..1 (64-row half)
  c.wc  = w & 1;                      // 0..1 (64-col half)
  c.r16 = lane & 15;
  c.kg  = lane >> 4;                  // 0..3

  f32x4 acc[4][4];
#pragma unroll
  for (int m = 0; m < 4; ++m)
#pragma unroll
    for (int n = 0; n < 4; ++n) {
      f32x4 z = {0.f, 0.f, 0.f, 0.f};
      acc[m][n] = z;
    }

  stage_tile(c, As0, Bs0, 0);
  wait_barrier();

  for (int kt = 0; kt < 16; kt += 2) {
    stage_tile(c, As1, Bs1, kt + 1);   // issue next-tile loads FIRST
    compute_tile(c, As0, Bs0, acc);    // 32 MFMA/wave hide the latency
    wait_barrier();
    if (kt + 2 < 16) stage_tile(c, As0, Bs0, kt + 2);
    compute_tile(c, As1, Bs1, acc);
    wait_barrier();
  }

  // epilogue: D layout col = lane&15, row = (lane>>4)*4 + r  [m89-verified]
#pragma unroll
  for (int m = 0; m < 4; ++m) {
#pragma unroll
    for (int r = 0; r < 4; ++r) {
      int row = row0 + c.wr * 64 + m * 16 + c.kg * 4 + r;
#pragma unroll
      for (int n = 0; n < 4; ++n) {
        int col = col0 + c.wc * 64 + n * 16 + c.r16;
        out[(size_t)row * 1024 + col] = to_bf16(acc[m][n][r]);
      }
    }
  }
}

// chunked XCD swizzle (512 blocks, 64/XCD = one gate per XCD = 4MB L2 fit)
__device__ __forceinline__ void swz_decode(int bx, int& g, int& row0, int& col0) {
  int wg = ((bx & 7) << 6) | (bx >> 3);
  g = wg >> 6;                         // 0..7
  int t = wg & 63;                     // 8 m-tiles x 8 n-tiles of 128^2
  row0 = (t >> 3) * 128;
  col0 = (t & 7) * 128;
}

// stage 1: T_g = L_g @ {x|h}   grid 512 x 256thr
__global__ __launch_bounds__(256) void gemm_stage1_kernel(
    const u16* __restrict__ Lb, const u16* __restrict__ xT,
    const u16* __restrict__ hT, u16* __restrict__ Tbuf)
{
  __shared__ u16 As0[128 * 64], Bs0[128 * 64];
  __shared__ u16 As1[128 * 64], Bs1[128 * 64];
  int g, row0, col0;
  swz_decode(blockIdx.x, g, row0, col0);
  const u16* A = Lb + ((size_t)g << 20);
  const u16* B = (g & 1) ? hT : xT;
  gemm_body(A, B, row0, col0, Tbuf + ((size_t)g << 20), As0, Bs0, As1, Bs1);
}

// stage 2: P_g = T_g @ R_g   grid 512 x 256thr; bias added in cell
__global__ __launch_bounds__(256) void gemm_stage2_kernel(
    const u16* __restrict__ Tbuf, const u16* __restrict__ RT,
    u16* __restrict__ P)
{
  __shared__ u16 As0[128 * 64], Bs0[128 * 64];
  __shared__ u16 As1[128 * 64], Bs1[128 * 64];
  int g, row0, col0;
  swz_decode(blockIdx.x, g, row0, col0);
  const u16* A = Tbuf + ((size_t)g << 20);
  const u16* B = RT   + ((size_t)g << 20);
  gemm_body(A, B, row0, col0, P + ((size_t)g << 20), As0, Bs0, As1, Bs1);
}

// cell: sums gate pairs + biases, applies nonlinearities
__global__ __launch_bounds__(256) void lstm_cell_kernel(
    const u16* __restrict__ P, B8 bp, const float* __restrict__ c,
    float* __restrict__ out)
{
  int i = (blockIdx.x * 256 + threadIdx.x) * 4;
  ushort4 pv[8];
#pragma unroll
  for (int g = 0; g < 8; ++g)
    pv[g] = *reinterpret_cast<const ushort4*>(P + (size_t)g * MAT_ELEMS + i);
  f32x4 bv[8];
#pragma unroll
  for (int g = 0; g < 8; ++g)
    bv[g] = *reinterpret_cast<const f32x4*>(bp.b[g] + i);
  f32x4 cc = *reinterpret_cast<const f32x4*>(c + i);
  f32x4 hn, cn;
#pragma unroll
  for (int j = 0; j < 4; ++j) {
    float pi = bf16_to_f32((&pv[0].x)[j]) + bf16_to_f32((&pv[1].x)[j]) + bv[0][j] + bv[1][j];
    float pf = bf16_to_f32((&pv[2].x)[j]) + bf16_to_f32((&pv[3].x)[j]) + bv[2][j] + bv[3][j];
    float pg = bf16_to_f32((&pv[4].x)[j]) + bf16_to_f32((&pv[5].x)[j]) + bv[4][j] + bv[5][j];
    float po = bf16_to_f32((&pv[6].x)[j]) + bf16_to_f32((&pv[7].x)[j]) + bv[6][j] + bv[7][j];
    float ig = fast_sigmoid(pi);
    float fg = fast_sigmoid(pf);
    float gg = fast_tanh(pg);
    float og = fast_sigmoid(po);
    float cv = fg * cc[j] + ig * gg;
    cn[j] = cv;
    hn[j] = og * fast_tanh(cv);
  }
  *reinterpret_cast<f32x4*>(out + i) = hn;
  *reinterpret_cast<f32x4*>(out + MAT_ELEMS + i) = cn;
}

// ---------- launch ----------

extern "C" void kernel_launch(void* const* d_in, const int* in_sizes, int n_in,
                              void* d_out, int out_size, void* d_ws, size_t ws_size,
                              hipStream_t stream) {
  const float* x = (const float*)d_in[0];
  const float* h = (const float*)d_in[1];
  const float* c = (const float*)d_in[2];

  // ws layout (68 MB):
  u16* Lb   = (u16*)d_ws;                         // 8 x 1M bf16 (16 MB)
  u16* xT   = Lb + ((size_t)8 << 20);             // 2 MB
  u16* hT   = xT + ((size_t)1 << 20);             // 2 MB
  u16* RT   = hT + ((size_t)1 << 20);             // 16 MB
  u16* Tbuf = RT + ((size_t)8 << 20);             // 16 MB
  u16* P    = Tbuf + ((size_t)8 << 20);           // 8 x 1M bf16 (16 MB)

  P8 lp;
  for (int g = 0; g < 8; ++g) lp.p[g] = (const float*)d_in[3 + 3 * g];
  P10 tp;
  tp.p[0] = x; tp.p[1] = h;
  for (int g = 0; g < 8; ++g) tp.p[2 + g] = (const float*)d_in[4 + 3 * g];
  B8 bp;
  for (int g = 0; g < 8; ++g) bp.b[g] = (const float*)d_in[5 + 3 * g];

  cast8_kernel<<<dim3(1024, 8), 256, 0, stream>>>(lp, Lb);
  transpose_cast_kernel<<<dim3(16, 32, 10), 256, 0, stream>>>(tp, xT);
  gemm_stage1_kernel<<<512, 256, 0, stream>>>(Lb, xT, hT, Tbuf);
  gemm_stage2_kernel<<<512, 256, 0, stream>>>(Tbuf, RT, P);
  lstm_cell_kernel<<<1024, 256, 0, stream>>>(P, bp, c, (float*)d_out);
}